// Round 1
// baseline (2386.468 us; speedup 1.0000x reference)
//
#include <hip/hip_runtime.h>
#include <hip/hip_bf16.h>
#include <math.h>

#define B_ 8
#define T_ 1024
#define F_ 256
#define H_ 256
#define BT_ (B_*T_)          // 8192
constexpr float EPS = 1e-5f;
constexpr float SCALE = 0.0625f;   // 1/sqrt(256)

typedef unsigned int u32;
typedef unsigned short u16;

// ---------- bf16 helpers (OCP bfloat16 via bit ops) ----------
__device__ __forceinline__ float bflo(u32 p) { return __uint_as_float(p << 16); }
__device__ __forceinline__ float bfhi(u32 p) { return __uint_as_float(p & 0xFFFF0000u); }
__device__ __forceinline__ u16 f2bf(float f) {
  u32 u = __float_as_uint(f);
  u32 r = u + 0x7FFFu + ((u >> 16) & 1u);   // RNE
  return (u16)(r >> 16);
}
__device__ __forceinline__ float4 bfp4(uint2 p) {
  float4 r;
  r.x = bflo(p.x); r.y = bfhi(p.x);
  r.z = bflo(p.y); r.w = bfhi(p.y);
  return r;
}

// ---------- block-wide reduction of 4 values over 256 threads ----------
__device__ __forceinline__ void block_reduce4(float& a, float& b, float& c, float& d) {
  #pragma unroll
  for (int off = 32; off > 0; off >>= 1) {
    a += __shfl_down(a, off, 64);
    b += __shfl_down(b, off, 64);
    c += __shfl_down(c, off, 64);
    d += __shfl_down(d, off, 64);
  }
  __shared__ float red[4][4];
  int wid = threadIdx.x >> 6;
  int lane = threadIdx.x & 63;
  if (lane == 0) { red[0][wid] = a; red[1][wid] = b; red[2][wid] = c; red[3][wid] = d; }
  __syncthreads();
  a = red[0][0] + red[0][1] + red[0][2] + red[0][3];
  b = red[1][0] + red[1][1] + red[1][2] + red[1][3];
  c = red[2][0] + red[2][1] + red[2][2] + red[2][3];
  d = red[3][0] + red[3][1] + red[3][2] + red[3][3];
}

// ---------- K1: LayerNorm over F per (b,t,plane); emit bf16 real/imag ----------
__global__ __launch_bounds__(256) void ln1_kernel(
    const float* __restrict__ x, const float* __restrict__ w, const float* __restrict__ bi,
    u16* __restrict__ xnr, u16* __restrict__ xni) {
  const int row = blockIdx.x;       // b*T + t
  const int f = threadIdx.x;
  float2 xv = reinterpret_cast<const float2*>(x)[row * F_ + f];  // (real, imag)
  float sr = xv.x, si = xv.y, sr2 = xv.x * xv.x, si2 = xv.y * xv.y;
  block_reduce4(sr, si, sr2, si2);
  const float inv = 1.0f / F_;
  float mr = sr * inv, mi = si * inv;
  float vr = sr2 * inv - mr * mr, vi = si2 * inv - mi * mi;
  float rr = rsqrtf(vr + EPS), ri = rsqrtf(vi + EPS);
  float ww = w[f], bb = bi[f];
  xnr[row * F_ + f] = f2bf((xv.x - mr) * rr * ww + bb);
  xni[row * F_ + f] = f2bf((xv.y - mi) * ri * ww + bb);
}

// ---------- K2: QKV projection GEMMs; z = m*8+n selects matrix & branch ----------
__global__ __launch_bounds__(256) void qkv_kernel(
    const u16* __restrict__ xnr, const u16* __restrict__ xni,
    const float* __restrict__ Wq, const float* __restrict__ bq,
    const float* __restrict__ Wk, const float* __restrict__ bk,
    const float* __restrict__ Wv, const float* __restrict__ bv,
    u16* __restrict__ qo, u16* __restrict__ ko, u16* __restrict__ vo) {
  const int z = blockIdx.z;
  const int m = z >> 3, n = z & 7;
  int sel; const float* W; const float* bias; u16* out;
  if (m == 0)      { sel = (n >> 1) & 1;  W = Wq; bias = bq; out = qo; }
  else if (m == 1) { sel = n & 1;         W = Wk; bias = bk; out = ko; }
  else             { sel = __popc(n) & 1; W = Wv; bias = bv; out = vo; }
  const u16* A = sel ? xni : xnr;
  W += n * F_ * H_; bias += n * H_; out += (size_t)n * BT_ * H_;
  const int rowbase = blockIdx.x * 64;
  const int colbase = blockIdx.y * 64;

  __shared__ float As[64][33];   // padded: conflict-free broadcast reads
  __shared__ float Ws[32][68];   // padded, 16B-aligned rows for float4

  const int tid = threadIdx.x;
  const int tr = tid >> 4, tc = tid & 15;
  float acc[4][4] = {};

  for (int kb = 0; kb < F_; kb += 32) {
    {   // stage A tile 64x32 (bf16 -> f32)
      int r = tid >> 2;
      int c8 = (tid & 3) * 8;
      uint4 p = *reinterpret_cast<const uint4*>(A + (size_t)(rowbase + r) * F_ + kb + c8);
      As[r][c8 + 0] = bflo(p.x); As[r][c8 + 1] = bfhi(p.x);
      As[r][c8 + 2] = bflo(p.y); As[r][c8 + 3] = bfhi(p.y);
      As[r][c8 + 4] = bflo(p.z); As[r][c8 + 5] = bfhi(p.z);
      As[r][c8 + 6] = bflo(p.w); As[r][c8 + 7] = bfhi(p.w);
    }
    {   // stage W tile 32x64 (f32)
      #pragma unroll
      for (int i = 0; i < 2; i++) {
        int id = tid + i * 256;
        int r = id >> 4;
        int c4 = (id & 15) * 4;
        float4 p = *reinterpret_cast<const float4*>(&W[(size_t)(kb + r) * H_ + colbase + c4]);
        *reinterpret_cast<float4*>(&Ws[r][c4]) = p;
      }
    }
    __syncthreads();
    #pragma unroll 8
    for (int kk = 0; kk < 32; kk++) {
      float a[4], wv[4];
      #pragma unroll
      for (int i = 0; i < 4; i++) a[i] = As[tr * 4 + i][kk];
      #pragma unroll
      for (int j = 0; j < 4; j++) wv[j] = Ws[kk][tc * 4 + j];
      #pragma unroll
      for (int i = 0; i < 4; i++)
        #pragma unroll
        for (int j = 0; j < 4; j++)
          acc[i][j] += a[i] * wv[j];
    }
    __syncthreads();
  }
  #pragma unroll
  for (int i = 0; i < 4; i++) {
    size_t r = rowbase + tr * 4 + i;
    #pragma unroll
    for (int j = 0; j < 4; j++) {
      int c = colbase + tc * 4 + j;
      out[r * H_ + c] = f2bf(acc[i][j] + bias[c]);
    }
  }
}

// ---------- K3: flash attention per (branch,batch); signed atomic combine ----------
__global__ __launch_bounds__(256) void attn_kernel(
    const u16* __restrict__ q, const u16* __restrict__ k, const u16* __restrict__ v,
    float* __restrict__ acc) {
  const int qt = blockIdx.x;         // 0..31 : 32 query rows each
  const int nb = blockIdx.y;         // 0..63 : n*8 + b
  const int n = nb >> 3, bb = nb & 7;
  const size_t base = (size_t)nb * T_ * H_;   // n*BT + b*T == nb*1024 rows
  const u16* qb = q + base;
  const u16* kbp = k + base;
  const u16* vbp = v + base;

  __shared__ __align__(16) u16 Qs[32][264];   // pad 264: rows offset 4 banks
  __shared__ __align__(16) u16 Ks[32][264];
  __shared__ __align__(16) u16 Vs[32][264];
  __shared__ float Ss[32][33];
  __shared__ float mrow[32], lrow[32], arow[32];

  const int tid = threadIdx.x;

  #pragma unroll
  for (int i = 0; i < 4; i++) {    // load Q tile
    int id = tid + i * 256;
    int r = id >> 5;
    int c8 = (id & 31) * 8;
    *reinterpret_cast<uint4*>(&Qs[r][c8]) =
        *reinterpret_cast<const uint4*>(qb + (size_t)(qt * 32 + r) * H_ + c8);
  }
  if (tid < 32) { mrow[tid] = -1e30f; lrow[tid] = 0.f; }

  const int rg = tid >> 4, hg = tid & 15;   // O: rows rg*2..+1, cols hg*16..+15
  float o[2][16] = {};
  const int sr = tid >> 3;                  // S: row
  const int sc = (tid & 7) * 4;             // S: col base

  for (int kt = 0; kt < 32; kt++) {
    __syncthreads();
    #pragma unroll
    for (int i = 0; i < 4; i++) {  // stage K,V tiles
      int id = tid + i * 256;
      int r = id >> 5;
      int c8 = (id & 31) * 8;
      *reinterpret_cast<uint4*>(&Ks[r][c8]) =
          *reinterpret_cast<const uint4*>(kbp + (size_t)(kt * 32 + r) * H_ + c8);
      *reinterpret_cast<uint4*>(&Vs[r][c8]) =
          *reinterpret_cast<const uint4*>(vbp + (size_t)(kt * 32 + r) * H_ + c8);
    }
    __syncthreads();
    // S = Q K^T * scale  (each thread: 1 row x 4 cols)
    float s0 = 0, s1 = 0, s2 = 0, s3 = 0;
    #pragma unroll 4
    for (int f = 0; f < H_; f += 4) {
      float4 qq = bfp4(*reinterpret_cast<const uint2*>(&Qs[sr][f]));
      float4 k0 = bfp4(*reinterpret_cast<const uint2*>(&Ks[sc + 0][f]));
      float4 k1 = bfp4(*reinterpret_cast<const uint2*>(&Ks[sc + 1][f]));
      float4 k2 = bfp4(*reinterpret_cast<const uint2*>(&Ks[sc + 2][f]));
      float4 k3 = bfp4(*reinterpret_cast<const uint2*>(&Ks[sc + 3][f]));
      s0 += qq.x * k0.x + qq.y * k0.y + qq.z * k0.z + qq.w * k0.w;
      s1 += qq.x * k1.x + qq.y * k1.y + qq.z * k1.z + qq.w * k1.w;
      s2 += qq.x * k2.x + qq.y * k2.y + qq.z * k2.z + qq.w * k2.w;
      s3 += qq.x * k3.x + qq.y * k3.y + qq.z * k3.z + qq.w * k3.w;
    }
    Ss[sr][sc + 0] = s0 * SCALE;
    Ss[sr][sc + 1] = s1 * SCALE;
    Ss[sr][sc + 2] = s2 * SCALE;
    Ss[sr][sc + 3] = s3 * SCALE;
    __syncthreads();
    if (tid < 32) {   // online softmax per row
      float mold = mrow[tid];
      float mx = mold;
      #pragma unroll
      for (int c = 0; c < 32; c++) mx = fmaxf(mx, Ss[tid][c]);
      float sum = 0.f;
      #pragma unroll
      for (int c = 0; c < 32; c++) {
        float p = __expf(Ss[tid][c] - mx);
        Ss[tid][c] = p;
        sum += p;
      }
      float al = __expf(mold - mx);
      lrow[tid] = lrow[tid] * al + sum;
      arow[tid] = al;
      mrow[tid] = mx;
    }
    __syncthreads();
    // O = O*alpha + P V
    #pragma unroll
    for (int i = 0; i < 2; i++) {
      float al = arow[rg * 2 + i];
      #pragma unroll
      for (int j = 0; j < 16; j++) o[i][j] *= al;
    }
    #pragma unroll 2
    for (int c = 0; c < 32; c++) {
      float p0 = Ss[rg * 2 + 0][c];
      float p1 = Ss[rg * 2 + 1][c];
      const u16* vp = &Vs[c][hg * 16];
      uint4 va = *reinterpret_cast<const uint4*>(vp);
      uint4 vb4 = *reinterpret_cast<const uint4*>(vp + 8);
      float vv[16];
      vv[0] = bflo(va.x);  vv[1] = bfhi(va.x);  vv[2] = bflo(va.y);  vv[3] = bfhi(va.y);
      vv[4] = bflo(va.z);  vv[5] = bfhi(va.z);  vv[6] = bflo(va.w);  vv[7] = bfhi(va.w);
      vv[8] = bflo(vb4.x); vv[9] = bfhi(vb4.x); vv[10] = bflo(vb4.y); vv[11] = bfhi(vb4.y);
      vv[12] = bflo(vb4.z); vv[13] = bfhi(vb4.z); vv[14] = bflo(vb4.w); vv[15] = bfhi(vb4.w);
      #pragma unroll
      for (int j = 0; j < 16; j++) {
        o[0][j] += p0 * vv[j];
        o[1][j] += p1 * vv[j];
      }
    }
  }
  // signed combine: real = o0-o1-o2-o3 (plane 0), imag = o4+o5+o6-o7 (plane 1)
  const float sign = (n == 0 || n == 4 || n == 5 || n == 6) ? 1.f : -1.f;
  const int plane = (n < 4) ? 0 : 1;
  #pragma unroll
  for (int i = 0; i < 2; i++) {
    int r = rg * 2 + i;
    float invl = 1.0f / lrow[r];
    size_t orow = (size_t)bb * T_ + qt * 32 + r;
    #pragma unroll
    for (int j = 0; j < 16; j++) {
      int h = hg * 16 + j;
      atomicAdd(&acc[(orow * H_ + h) * 2 + plane], sign * o[i][j] * invl);
    }
  }
}

// ---------- K4: LayerNorm over H per (b,t,plane) ----------
__global__ __launch_bounds__(256) void ln2_kernel(
    const float* __restrict__ accv, const float* __restrict__ w,
    const float* __restrict__ bi, float* __restrict__ out) {
  const int row = blockIdx.x;
  const int h = threadIdx.x;
  float2 xv = reinterpret_cast<const float2*>(accv)[row * H_ + h];
  float sr = xv.x, si = xv.y, sr2 = xv.x * xv.x, si2 = xv.y * xv.y;
  block_reduce4(sr, si, sr2, si2);
  const float inv = 1.0f / H_;
  float mr = sr * inv, mi = si * inv;
  float vr = sr2 * inv - mr * mr, vi = si2 * inv - mi * mi;
  float rr = rsqrtf(vr + EPS), ri = rsqrtf(vi + EPS);
  float ww = w[h], bb = bi[h];
  float2 res;
  res.x = (xv.x - mr) * rr * ww + bb;
  res.y = (xv.y - mi) * ri * ww + bb;
  reinterpret_cast<float2*>(out)[row * H_ + h] = res;
}

extern "C" void kernel_launch(void* const* d_in, const int* in_sizes, int n_in,
                              void* d_out, int out_size, void* d_ws, size_t ws_size,
                              hipStream_t stream) {
  const float* x    = (const float*)d_in[0];
  const float* Wq   = (const float*)d_in[1];
  const float* bq   = (const float*)d_in[2];
  const float* Wk   = (const float*)d_in[3];
  const float* bk   = (const float*)d_in[4];
  const float* Wv   = (const float*)d_in[5];
  const float* bv   = (const float*)d_in[6];
  const float* ln1w = (const float*)d_in[7];
  const float* ln1b = (const float*)d_in[8];
  const float* ln2w = (const float*)d_in[9];
  const float* ln2b = (const float*)d_in[10];

  char* ws = (char*)d_ws;
  u16* xnr   = (u16*)(ws);                          // 4 MB
  u16* xni   = (u16*)(ws + (4ull  << 20));          // 4 MB
  u16* qbuf  = (u16*)(ws + (8ull  << 20));          // 32 MB
  u16* kbuf  = (u16*)(ws + (40ull << 20));          // 32 MB
  u16* vbuf  = (u16*)(ws + (72ull << 20));          // 32 MB
  float* acc = (float*)(ws + (104ull << 20));       // 16 MB  (total 120 MB)

  hipMemsetAsync(acc, 0, (size_t)BT_ * H_ * 2 * sizeof(float), stream);
  ln1_kernel<<<BT_, 256, 0, stream>>>(x, ln1w, ln1b, xnr, xni);
  qkv_kernel<<<dim3(128, 4, 24), 256, 0, stream>>>(xnr, xni, Wq, bq, Wk, bk, Wv, bv,
                                                   qbuf, kbuf, vbuf);
  attn_kernel<<<dim3(32, 64), 256, 0, stream>>>(qbuf, kbuf, vbuf, acc);
  ln2_kernel<<<BT_, 256, 0, stream>>>(acc, ln2w, ln2b, (float*)d_out);
}

// Round 2
// 719.896 us; speedup vs baseline: 3.3150x; 3.3150x over previous
//
#include <hip/hip_runtime.h>
#include <math.h>

#define B_ 8
#define T_ 1024
#define F_ 256
#define H_ 256
#define BT_ (B_*T_)          // 8192
constexpr float EPS = 1e-5f;
constexpr float SCALE = 0.0625f;   // 1/sqrt(256)

typedef unsigned int u32;
typedef unsigned short u16;
typedef __attribute__((ext_vector_type(8))) short bf16x8;   // 8 bf16 = 4 VGPRs
typedef __attribute__((ext_vector_type(4))) float f32x4;

// ---------- bf16 helpers ----------
__device__ __forceinline__ float bflo(u32 p) { return __uint_as_float(p << 16); }
__device__ __forceinline__ float bfhi(u32 p) { return __uint_as_float(p & 0xFFFF0000u); }
__device__ __forceinline__ float bf1(u16 p) { return __uint_as_float(((u32)p) << 16); }
__device__ __forceinline__ u16 f2bf(float f) {
  u32 u = __float_as_uint(f);
  u32 r = u + 0x7FFFu + ((u >> 16) & 1u);   // RNE
  return (u16)(r >> 16);
}

__device__ __forceinline__ f32x4 mfma16(bf16x8 a, bf16x8 b, f32x4 c) {
  return __builtin_amdgcn_mfma_f32_16x16x32_bf16(a, b, c, 0, 0, 0);
}

// ---------- block-wide reduction of 4 values over 256 threads ----------
__device__ __forceinline__ void block_reduce4(float& a, float& b, float& c, float& d) {
  #pragma unroll
  for (int off = 32; off > 0; off >>= 1) {
    a += __shfl_down(a, off, 64);
    b += __shfl_down(b, off, 64);
    c += __shfl_down(c, off, 64);
    d += __shfl_down(d, off, 64);
  }
  __shared__ float red[4][4];
  int wid = threadIdx.x >> 6;
  int lane = threadIdx.x & 63;
  if (lane == 0) { red[0][wid] = a; red[1][wid] = b; red[2][wid] = c; red[3][wid] = d; }
  __syncthreads();
  a = red[0][0] + red[0][1] + red[0][2] + red[0][3];
  b = red[1][0] + red[1][1] + red[1][2] + red[1][3];
  c = red[2][0] + red[2][1] + red[2][2] + red[2][3];
  d = red[3][0] + red[3][1] + red[3][2] + red[3][3];
}

// ---------- K1: LayerNorm over F per (b,t,plane); emit bf16 real/imag ----------
__global__ __launch_bounds__(256) void ln1_kernel(
    const float* __restrict__ x, const float* __restrict__ w, const float* __restrict__ bi,
    u16* __restrict__ xnr, u16* __restrict__ xni) {
  const int row = blockIdx.x;
  const int f = threadIdx.x;
  float2 xv = reinterpret_cast<const float2*>(x)[row * F_ + f];
  float sr = xv.x, si = xv.y, sr2 = xv.x * xv.x, si2 = xv.y * xv.y;
  block_reduce4(sr, si, sr2, si2);
  const float inv = 1.0f / F_;
  float mr = sr * inv, mi = si * inv;
  float vr = sr2 * inv - mr * mr, vi = si2 * inv - mi * mi;
  float rr = rsqrtf(vr + EPS), ri = rsqrtf(vi + EPS);
  float ww = w[f], bb = bi[f];
  xnr[row * F_ + f] = f2bf((xv.x - mr) * rr * ww + bb);
  xni[row * F_ + f] = f2bf((xv.y - mi) * ri * ww + bb);
}

// ---------- K2: QKV projection GEMMs (unchanged VALU version this round) ----------
__global__ __launch_bounds__(256) void qkv_kernel(
    const u16* __restrict__ xnr, const u16* __restrict__ xni,
    const float* __restrict__ Wq, const float* __restrict__ bq,
    const float* __restrict__ Wk, const float* __restrict__ bk,
    const float* __restrict__ Wv, const float* __restrict__ bv,
    u16* __restrict__ qo, u16* __restrict__ ko, u16* __restrict__ vo) {
  const int z = blockIdx.z;
  const int m = z >> 3, n = z & 7;
  int sel; const float* W; const float* bias; u16* out;
  if (m == 0)      { sel = (n >> 1) & 1;  W = Wq; bias = bq; out = qo; }
  else if (m == 1) { sel = n & 1;         W = Wk; bias = bk; out = ko; }
  else             { sel = __popc(n) & 1; W = Wv; bias = bv; out = vo; }
  const u16* A = sel ? xni : xnr;
  W += n * F_ * H_; bias += n * H_; out += (size_t)n * BT_ * H_;
  const int rowbase = blockIdx.x * 64;
  const int colbase = blockIdx.y * 64;

  __shared__ float As[64][33];
  __shared__ float Ws[32][68];

  const int tid = threadIdx.x;
  const int tr = tid >> 4, tc = tid & 15;
  float acc[4][4] = {};

  for (int kb = 0; kb < F_; kb += 32) {
    {
      int r = tid >> 2;
      int c8 = (tid & 3) * 8;
      uint4 p = *reinterpret_cast<const uint4*>(A + (size_t)(rowbase + r) * F_ + kb + c8);
      As[r][c8 + 0] = bflo(p.x); As[r][c8 + 1] = bfhi(p.x);
      As[r][c8 + 2] = bflo(p.y); As[r][c8 + 3] = bfhi(p.y);
      As[r][c8 + 4] = bflo(p.z); As[r][c8 + 5] = bfhi(p.z);
      As[r][c8 + 6] = bflo(p.w); As[r][c8 + 7] = bfhi(p.w);
    }
    {
      #pragma unroll
      for (int i = 0; i < 2; i++) {
        int id = tid + i * 256;
        int r = id >> 4;
        int c4 = (id & 15) * 4;
        float4 p = *reinterpret_cast<const float4*>(&W[(size_t)(kb + r) * H_ + colbase + c4]);
        *reinterpret_cast<float4*>(&Ws[r][c4]) = p;
      }
    }
    __syncthreads();
    #pragma unroll 8
    for (int kk = 0; kk < 32; kk++) {
      float a[4], wv[4];
      #pragma unroll
      for (int i = 0; i < 4; i++) a[i] = As[tr * 4 + i][kk];
      #pragma unroll
      for (int j = 0; j < 4; j++) wv[j] = Ws[kk][tc * 4 + j];
      #pragma unroll
      for (int i = 0; i < 4; i++)
        #pragma unroll
        for (int j = 0; j < 4; j++)
          acc[i][j] += a[i] * wv[j];
    }
    __syncthreads();
  }
  #pragma unroll
  for (int i = 0; i < 4; i++) {
    size_t r = rowbase + tr * 4 + i;
    #pragma unroll
    for (int j = 0; j < 4; j++) {
      int c = colbase + tc * 4 + j;
      out[r * H_ + c] = f2bf(acc[i][j] + bias[c]);
    }
  }
}

// ---------- K3: transpose v [n][BT][H] -> vT [n][H][B][T] ----------
__global__ __launch_bounds__(256) void vtrans_kernel(
    const u16* __restrict__ v, u16* __restrict__ vT) {
  const int nb = blockIdx.z;
  const int n = nb >> 3, b = nb & 7;
  const int tt = blockIdx.x;   // t-tile (64)
  const int ht = blockIdx.y;   // h-tile (64)
  __shared__ u16 Ts[64][72];   // rows=t, cols=h; 144B rows keep 16B align

  const int tid = threadIdx.x;
  const u16* vp = v + ((size_t)n * BT_ + b * T_ + tt * 64) * H_ + ht * 64;
  #pragma unroll
  for (int i = 0; i < 2; i++) {   // coalesced 64x64 load
    int id = tid + i * 256;
    int r = id >> 3, c8 = (id & 7) * 8;
    *reinterpret_cast<uint4*>(&Ts[r][c8]) =
        *reinterpret_cast<const uint4*>(vp + (size_t)r * H_ + c8);
  }
  __syncthreads();
  u16* op = vT + (((size_t)n * H_ + ht * 64) * B_ + b) * T_ + tt * 64;
  #pragma unroll
  for (int i = 0; i < 2; i++) {   // hl = lane -> conflict-free column reads
    int id = tid + i * 256;
    int hl = id & 63, g = id >> 6;
    u16 tmp[8];
    #pragma unroll
    for (int j = 0; j < 8; j++) tmp[j] = Ts[g * 8 + j][hl];
    *reinterpret_cast<uint4*>(op + (size_t)hl * B_ * T_ + g * 8) =
        *reinterpret_cast<const uint4*>(tmp);
  }
}

// ---------- K4: MFMA flash attention; per-branch O (pre-normalized) to obuf ----------
__global__ __launch_bounds__(256, 3) void attn_kernel(
    const u16* __restrict__ q, const u16* __restrict__ k, const u16* __restrict__ vT,
    u16* __restrict__ obuf) {
  const int qt = blockIdx.x;         // 0..15 : 64 query rows each
  const int nb = blockIdx.y;         // n*8 + b
  const int n = nb >> 3, b = nb & 7;
  const int tid = threadIdx.x;
  const int wv = tid >> 6, lane = tid & 63;
  const int quad = lane >> 4, l16 = lane & 15;

  const size_t base = (size_t)nb * T_ * H_;
  const u16* qp = q + base;
  const u16* kp = k + base;
  const u16* vtp = vT + ((size_t)n * H_ * B_ + b) * T_;

  __shared__ u16 Ks[32][264];     // rows=key (pad 8 -> 528B rows, 16B aligned)
  __shared__ u16 Vs[H_][40];      // rows=h, cols=key (pad 8 -> 80B rows)
  __shared__ u16 Ps[4][16][40];   // per-wave P scratch (C/D -> A layout)

  // Q fragments: rows qrow0..+15 for this wave, resident in registers
  const int qrow0 = qt * 64 + wv * 16;
  bf16x8 qf[8];
  #pragma unroll
  for (int kc = 0; kc < 8; kc++)
    qf[kc] = *reinterpret_cast<const bf16x8*>(
        qp + (size_t)(qrow0 + l16) * H_ + kc * 32 + quad * 8);

  f32x4 o[16];
  #pragma unroll
  for (int ct = 0; ct < 16; ct++) o[ct] = (f32x4){0.f, 0.f, 0.f, 0.f};
  float mrow[4] = {-1e30f, -1e30f, -1e30f, -1e30f};
  float lrow[4] = {0.f, 0.f, 0.f, 0.f};

  #pragma unroll 1
  for (int kt = 0; kt < 32; kt++) {
    __syncthreads();
    #pragma unroll
    for (int i = 0; i < 4; i++) {   // stage K tile 32x256
      int id = tid + i * 256;
      int r = id >> 5, c8 = (id & 31) * 8;
      *reinterpret_cast<uint4*>(&Ks[r][c8]) =
          *reinterpret_cast<const uint4*>(kp + (size_t)(kt * 32 + r) * H_ + c8);
    }
    #pragma unroll
    for (int i = 0; i < 4; i++) {   // stage Vt tile 256x32 (already transposed)
      int id = tid + i * 256;
      int h = id >> 2, g = id & 3;
      *reinterpret_cast<uint4*>(&Vs[h][g * 8]) =
          *reinterpret_cast<const uint4*>(vtp + (size_t)h * B_ * T_ + kt * 32 + g * 8);
    }
    __syncthreads();

    // S = Q K^T (16 q-rows x 32 keys per wave)
    f32x4 s0 = {0.f, 0.f, 0.f, 0.f}, s1 = {0.f, 0.f, 0.f, 0.f};
    #pragma unroll
    for (int kc = 0; kc < 8; kc++) {
      bf16x8 k0 = *reinterpret_cast<const bf16x8*>(&Ks[l16][kc * 32 + quad * 8]);
      bf16x8 k1 = *reinterpret_cast<const bf16x8*>(&Ks[16 + l16][kc * 32 + quad * 8]);
      s0 = mfma16(qf[kc], k0, s0);
      s1 = mfma16(qf[kc], k1, s1);
    }
    s0 *= SCALE; s1 *= SCALE;

    // online softmax: row r = quad*4+r, stats uniform across l16 after xor-reduce
    float mx[4], al[4];
    #pragma unroll
    for (int r = 0; r < 4; r++) mx[r] = fmaxf(s0[r], s1[r]);
    #pragma unroll
    for (int off = 1; off < 16; off <<= 1)
      #pragma unroll
      for (int r = 0; r < 4; r++) mx[r] = fmaxf(mx[r], __shfl_xor(mx[r], off, 64));
    f32x4 p0, p1;
    float rs[4];
    #pragma unroll
    for (int r = 0; r < 4; r++) {
      float mn = fmaxf(mrow[r], mx[r]);
      al[r] = __expf(mrow[r] - mn);
      mrow[r] = mn;
      p0[r] = __expf(s0[r] - mn);
      p1[r] = __expf(s1[r] - mn);
      rs[r] = p0[r] + p1[r];
    }
    #pragma unroll
    for (int off = 1; off < 16; off <<= 1)
      #pragma unroll
      for (int r = 0; r < 4; r++) rs[r] += __shfl_xor(rs[r], off, 64);
    #pragma unroll
    for (int r = 0; r < 4; r++) lrow[r] = lrow[r] * al[r] + rs[r];

    // P: C/D layout -> A layout via wave-private LDS (lockstep, no barrier)
    #pragma unroll
    for (int r = 0; r < 4; r++) {
      Ps[wv][quad * 4 + r][l16]      = f2bf(p0[r]);
      Ps[wv][quad * 4 + r][16 + l16] = f2bf(p1[r]);
    }
    #pragma unroll
    for (int ct = 0; ct < 16; ct++)
      #pragma unroll
      for (int r = 0; r < 4; r++) o[ct][r] *= al[r];
    bf16x8 pf = *reinterpret_cast<const bf16x8*>(&Ps[wv][l16][quad * 8]);
    #pragma unroll
    for (int ct = 0; ct < 16; ct++) {
      bf16x8 vf = *reinterpret_cast<const bf16x8*>(&Vs[ct * 16 + l16][quad * 8]);
      o[ct] = mfma16(pf, vf, o[ct]);
    }
  }

  // epilogue: normalize, repack via Ps, coalesced 16B stores
  float invl[4];
  #pragma unroll
  for (int r = 0; r < 4; r++) invl[r] = 1.0f / lrow[r];
  u16* ob = obuf + base;
  #pragma unroll
  for (int pair = 0; pair < 8; pair++) {
    #pragma unroll
    for (int r = 0; r < 4; r++) {
      Ps[wv][quad * 4 + r][l16]      = f2bf(o[2 * pair][r] * invl[r]);
      Ps[wv][quad * 4 + r][16 + l16] = f2bf(o[2 * pair + 1][r] * invl[r]);
    }
    uint4 val = *reinterpret_cast<const uint4*>(&Ps[wv][l16][quad * 8]);
    *reinterpret_cast<uint4*>(ob + (size_t)(qrow0 + l16) * H_ + pair * 32 + quad * 8) = val;
  }
}

// ---------- K5: combine 8 branches (signed) + LayerNorm over H ----------
__global__ __launch_bounds__(256) void combine_ln2_kernel(
    const u16* __restrict__ obuf, const float* __restrict__ w,
    const float* __restrict__ bi, float* __restrict__ out) {
  const int row = blockIdx.x;
  const int h = threadIdx.x;
  float o[8];
  #pragma unroll
  for (int nn = 0; nn < 8; nn++)
    o[nn] = bf1(obuf[(size_t)nn * BT_ * H_ + (size_t)row * H_ + h]);
  float re = o[0] - o[1] - o[2] - o[3];
  float im = o[4] + o[5] + o[6] - o[7];
  float sr = re, si = im, sr2 = re * re, si2 = im * im;
  block_reduce4(sr, si, sr2, si2);
  const float inv = 1.0f / H_;
  float mr = sr * inv, mi = si * inv;
  float vr = sr2 * inv - mr * mr, vi = si2 * inv - mi * mi;
  float rr = rsqrtf(vr + EPS), ri = rsqrtf(vi + EPS);
  float ww = w[h], bb = bi[h];
  float2 res;
  res.x = (re - mr) * rr * ww + bb;
  res.y = (im - mi) * ri * ww + bb;
  reinterpret_cast<float2*>(out)[(size_t)row * H_ + h] = res;
}

extern "C" void kernel_launch(void* const* d_in, const int* in_sizes, int n_in,
                              void* d_out, int out_size, void* d_ws, size_t ws_size,
                              hipStream_t stream) {
  const float* x    = (const float*)d_in[0];
  const float* Wq   = (const float*)d_in[1];
  const float* bq   = (const float*)d_in[2];
  const float* Wk   = (const float*)d_in[3];
  const float* bk   = (const float*)d_in[4];
  const float* Wv   = (const float*)d_in[5];
  const float* bv   = (const float*)d_in[6];
  const float* ln1w = (const float*)d_in[7];
  const float* ln1b = (const float*)d_in[8];
  const float* ln2w = (const float*)d_in[9];
  const float* ln2b = (const float*)d_in[10];

  // Workspace layout (128 MB), with lifetime-based aliasing:
  //  [0,32)   vT   (xn occupies [0,8) only until qkv completes)
  //  [32,64)  q
  //  [64,96)  k
  //  [96,128) v, then obuf (v is dead after vtrans; attn reads vT, not v)
  char* ws = (char*)d_ws;
  u16* xnr  = (u16*)(ws);
  u16* xni  = (u16*)(ws + (4ull  << 20));
  u16* vT   = (u16*)(ws);
  u16* qbuf = (u16*)(ws + (32ull << 20));
  u16* kbuf = (u16*)(ws + (64ull << 20));
  u16* vbuf = (u16*)(ws + (96ull << 20));
  u16* obuf = (u16*)(ws + (96ull << 20));

  ln1_kernel<<<BT_, 256, 0, stream>>>(x, ln1w, ln1b, xnr, xni);
  qkv_kernel<<<dim3(128, 4, 24), 256, 0, stream>>>(xnr, xni, Wq, bq, Wk, bk, Wv, bv,
                                                   qbuf, kbuf, vbuf);
  vtrans_kernel<<<dim3(16, 4, 64), 256, 0, stream>>>(vbuf, vT);
  attn_kernel<<<dim3(16, 64), 256, 0, stream>>>(qbuf, kbuf, vT, obuf);
  combine_ln2_kernel<<<BT_, 256, 0, stream>>>(obuf, ln2w, ln2b, (float*)d_out);
}

// Round 3
// 438.353 us; speedup vs baseline: 5.4442x; 1.6423x over previous
//
#include <hip/hip_runtime.h>
#include <math.h>

#define B_ 8
#define T_ 1024
#define F_ 256
#define H_ 256
#define BT_ (B_*T_)          // 8192
constexpr float EPS = 1e-5f;
constexpr float SCALE = 0.0625f;   // 1/sqrt(256)

typedef unsigned int u32;
typedef unsigned short u16;
typedef __attribute__((ext_vector_type(8))) short bf16x8;   // 8 bf16 = 4 VGPRs
typedef __attribute__((ext_vector_type(4))) float f32x4;

// ---------- bf16 helpers ----------
__device__ __forceinline__ float bflo(u32 p) { return __uint_as_float(p << 16); }
__device__ __forceinline__ float bfhi(u32 p) { return __uint_as_float(p & 0xFFFF0000u); }
__device__ __forceinline__ float bf1(u16 p) { return __uint_as_float(((u32)p) << 16); }
__device__ __forceinline__ u16 f2bf(float f) {
  u32 u = __float_as_uint(f);
  u32 r = u + 0x7FFFu + ((u >> 16) & 1u);   // RNE
  return (u16)(r >> 16);
}

__device__ __forceinline__ f32x4 mfma16(bf16x8 a, bf16x8 b, f32x4 c) {
  return __builtin_amdgcn_mfma_f32_16x16x32_bf16(a, b, c, 0, 0, 0);
}

// async global->LDS, 16B per lane; dest = wave-uniform base + lane*16
__device__ __forceinline__ void gload_lds16(const u16* g, u16* l) {
  __builtin_amdgcn_global_load_lds(
      (const __attribute__((address_space(1))) u32*)(uintptr_t)g,
      (__attribute__((address_space(3))) u32*)(u32)(uintptr_t)l,
      16, 0, 0);
}

// ---------- block-wide reduction of 4 values over 256 threads ----------
__device__ __forceinline__ void block_reduce4(float& a, float& b, float& c, float& d) {
  #pragma unroll
  for (int off = 32; off > 0; off >>= 1) {
    a += __shfl_down(a, off, 64);
    b += __shfl_down(b, off, 64);
    c += __shfl_down(c, off, 64);
    d += __shfl_down(d, off, 64);
  }
  __shared__ float red[4][4];
  int wid = threadIdx.x >> 6;
  int lane = threadIdx.x & 63;
  if (lane == 0) { red[0][wid] = a; red[1][wid] = b; red[2][wid] = c; red[3][wid] = d; }
  __syncthreads();
  a = red[0][0] + red[0][1] + red[0][2] + red[0][3];
  b = red[1][0] + red[1][1] + red[1][2] + red[1][3];
  c = red[2][0] + red[2][1] + red[2][2] + red[2][3];
  d = red[3][0] + red[3][1] + red[3][2] + red[3][3];
}

// ---------- K1: LayerNorm over F per (b,t,plane); emit bf16 real/imag ----------
__global__ __launch_bounds__(256) void ln1_kernel(
    const float* __restrict__ x, const float* __restrict__ w, const float* __restrict__ bi,
    u16* __restrict__ xnr, u16* __restrict__ xni) {
  const int row = blockIdx.x;
  const int f = threadIdx.x;
  float2 xv = reinterpret_cast<const float2*>(x)[row * F_ + f];
  float sr = xv.x, si = xv.y, sr2 = xv.x * xv.x, si2 = xv.y * xv.y;
  block_reduce4(sr, si, sr2, si2);
  const float inv = 1.0f / F_;
  float mr = sr * inv, mi = si * inv;
  float vr = sr2 * inv - mr * mr, vi = si2 * inv - mi * mi;
  float rr = rsqrtf(vr + EPS), ri = rsqrtf(vi + EPS);
  float ww = w[f], bb = bi[f];
  xnr[row * F_ + f] = f2bf((xv.x - mr) * rr * ww + bb);
  xni[row * F_ + f] = f2bf((xv.y - mi) * ri * ww + bb);
}

// ---------- K2a: weight prep — transpose+convert W[z][f][h] (f32) -> wT[z][h][f] (bf16) ----------
__global__ __launch_bounds__(256) void wprep_kernel(
    const float* __restrict__ Wq, const float* __restrict__ Wk, const float* __restrict__ Wv,
    u16* __restrict__ wT) {
  const int z = blockIdx.z;
  const int m = z >> 3, n = z & 7;
  const float* W = (m == 0 ? Wq : (m == 1 ? Wk : Wv)) + (size_t)n * F_ * H_;
  const int ft = blockIdx.x * 64;   // f tile
  const int ht = blockIdx.y * 64;   // h tile
  __shared__ __align__(16) u16 Ts[64][72];

  const int tid = threadIdx.x;
  #pragma unroll
  for (int i = 0; i < 4; i++) {   // load 64x64 f32, convert
    int id = tid + i * 256;
    int r = id >> 4, c4 = (id & 15) * 4;
    float4 p = *reinterpret_cast<const float4*>(&W[(size_t)(ft + r) * H_ + ht + c4]);
    Ts[r][c4 + 0] = f2bf(p.x); Ts[r][c4 + 1] = f2bf(p.y);
    Ts[r][c4 + 2] = f2bf(p.z); Ts[r][c4 + 3] = f2bf(p.w);
  }
  __syncthreads();
  u16* op = wT + (size_t)z * F_ * H_ + (size_t)ht * F_ + ft;
  #pragma unroll
  for (int i = 0; i < 2; i++) {   // transposed write, coalesced uint4
    int id = tid + i * 256;
    int hl = id & 63, g = id >> 6;
    u16 tmp[8];
    #pragma unroll
    for (int j = 0; j < 8; j++) tmp[j] = Ts[g * 8 + j][hl];
    *reinterpret_cast<uint4*>(op + (size_t)hl * F_ + g * 8) =
        *reinterpret_cast<const uint4*>(tmp);
  }
}

// ---------- K2b: QKV projections — bf16 MFMA GEMM, 128x128 tile ----------
__global__ __launch_bounds__(256) void qkv_kernel(
    const u16* __restrict__ xnr, const u16* __restrict__ xni, const u16* __restrict__ wT,
    const float* __restrict__ bq, const float* __restrict__ bk, const float* __restrict__ bv,
    u16* __restrict__ qo, u16* __restrict__ ko, u16* __restrict__ vo) {
  const int z = blockIdx.z;
  const int m = z >> 3, n = z & 7;
  int sel; const float* bias; u16* out;
  if (m == 0)      { sel = (n >> 1) & 1;  bias = bq; out = qo; }
  else if (m == 1) { sel = n & 1;         bias = bk; out = ko; }
  else             { sel = __popc(n) & 1; bias = bv; out = vo; }
  const u16* A = sel ? xni : xnr;
  const u16* wp = wT + (size_t)z * F_ * H_;
  bias += n * H_; out += (size_t)n * BT_ * H_;
  const int rowbase = blockIdx.x * 128;
  const int colbase = blockIdx.y * 128;

  __shared__ __align__(16) u16 As[128 * 32];   // [row][k], linear (global_load_lds order)
  __shared__ __align__(16) u16 Bs[128 * 32];   // [n][k],  linear
  __shared__ __align__(16) u16 Es[4][16][72];  // per-wave epilogue repack

  const int tid = threadIdx.x;
  const int wv = tid >> 6, lane = tid & 63;
  const int quad = lane >> 4, l16 = lane & 15;
  const int wrow = wv >> 1, wcol = wv & 1;

  f32x4 acc[4][4];
  #pragma unroll
  for (int i = 0; i < 4; i++)
    #pragma unroll
    for (int j = 0; j < 4; j++) acc[i][j] = (f32x4){0.f, 0.f, 0.f, 0.f};

  const int idx0 = (wv * 2) * 512 + lane * 8;       // bf16 index, chunk 2w
  const int idx1 = (wv * 2 + 1) * 512 + lane * 8;   // chunk 2w+1
  const int r0 = idx0 >> 5, k0 = idx0 & 31;
  const int r1 = idx1 >> 5, k1 = idx1 & 31;

  #pragma unroll 1
  for (int kb = 0; kb < F_; kb += 32) {
    gload_lds16(A + (size_t)(rowbase + r0) * F_ + kb + k0, &As[idx0]);
    gload_lds16(A + (size_t)(rowbase + r1) * F_ + kb + k1, &As[idx1]);
    gload_lds16(wp + (size_t)(colbase + r0) * F_ + kb + k0, &Bs[idx0]);
    gload_lds16(wp + (size_t)(colbase + r1) * F_ + kb + k1, &Bs[idx1]);
    __syncthreads();
    bf16x8 a[4], b[4];
    #pragma unroll
    for (int mi = 0; mi < 4; mi++)
      a[mi] = *reinterpret_cast<const bf16x8*>(
          &As[(wrow * 64 + mi * 16 + l16) * 32 + quad * 8]);
    #pragma unroll
    for (int nj = 0; nj < 4; nj++)
      b[nj] = *reinterpret_cast<const bf16x8*>(
          &Bs[(wcol * 64 + nj * 16 + l16) * 32 + quad * 8]);
    #pragma unroll
    for (int mi = 0; mi < 4; mi++)
      #pragma unroll
      for (int nj = 0; nj < 4; nj++)
        acc[mi][nj] = mfma16(a[mi], b[nj], acc[mi][nj]);
    __syncthreads();
  }

  // epilogue: + bias, repack C/D -> row-major via wave-private LDS, 16B stores
  float bias4[4];
  #pragma unroll
  for (int nj = 0; nj < 4; nj++)
    bias4[nj] = bias[colbase + wcol * 64 + nj * 16 + l16];
  #pragma unroll
  for (int mi = 0; mi < 4; mi++) {
    #pragma unroll
    for (int nj = 0; nj < 4; nj++)
      #pragma unroll
      for (int r = 0; r < 4; r++)
        Es[wv][quad * 4 + r][nj * 16 + l16] = f2bf(acc[mi][nj][r] + bias4[nj]);
    int row = rowbase + wrow * 64 + mi * 16 + l16;
    uint4 v0 = *reinterpret_cast<const uint4*>(&Es[wv][l16][quad * 16]);
    uint4 v1 = *reinterpret_cast<const uint4*>(&Es[wv][l16][quad * 16 + 8]);
    u16* op = out + (size_t)row * H_ + colbase + wcol * 64 + quad * 16;
    *reinterpret_cast<uint4*>(op) = v0;
    *reinterpret_cast<uint4*>(op + 8) = v1;
  }
}

// ---------- K3: transpose v [n][BT][H] -> vT [n][H][B][T] ----------
__global__ __launch_bounds__(256) void vtrans_kernel(
    const u16* __restrict__ v, u16* __restrict__ vT) {
  const int nb = blockIdx.z;
  const int n = nb >> 3, b = nb & 7;
  const int tt = blockIdx.x;
  const int ht = blockIdx.y;
  __shared__ u16 Ts[64][72];

  const int tid = threadIdx.x;
  const u16* vp = v + ((size_t)n * BT_ + b * T_ + tt * 64) * H_ + ht * 64;
  #pragma unroll
  for (int i = 0; i < 2; i++) {
    int id = tid + i * 256;
    int r = id >> 3, c8 = (id & 7) * 8;
    *reinterpret_cast<uint4*>(&Ts[r][c8]) =
        *reinterpret_cast<const uint4*>(vp + (size_t)r * H_ + c8);
  }
  __syncthreads();
  u16* op = vT + (((size_t)n * H_ + ht * 64) * B_ + b) * T_ + tt * 64;
  #pragma unroll
  for (int i = 0; i < 2; i++) {
    int id = tid + i * 256;
    int hl = id & 63, g = id >> 6;
    u16 tmp[8];
    #pragma unroll
    for (int j = 0; j < 8; j++) tmp[j] = Ts[g * 8 + j][hl];
    *reinterpret_cast<uint4*>(op + (size_t)hl * B_ * T_ + g * 8) =
        *reinterpret_cast<const uint4*>(tmp);
  }
}

// ---------- K4: MFMA flash attention; per-branch O (pre-normalized) to obuf ----------
__global__ __launch_bounds__(256, 3) void attn_kernel(
    const u16* __restrict__ q, const u16* __restrict__ k, const u16* __restrict__ vT,
    u16* __restrict__ obuf) {
  const int qt = blockIdx.x;
  const int nb = blockIdx.y;
  const int n = nb >> 3, b = nb & 7;
  const int tid = threadIdx.x;
  const int wv = tid >> 6, lane = tid & 63;
  const int quad = lane >> 4, l16 = lane & 15;

  const size_t base = (size_t)nb * T_ * H_;
  const u16* qp = q + base;
  const u16* kp = k + base;
  const u16* vtp = vT + ((size_t)n * H_ * B_ + b) * T_;

  __shared__ u16 Ks[32][264];
  __shared__ u16 Vs[H_][40];
  __shared__ u16 Ps[4][16][40];

  const int qrow0 = qt * 64 + wv * 16;
  bf16x8 qf[8];
  #pragma unroll
  for (int kc = 0; kc < 8; kc++)
    qf[kc] = *reinterpret_cast<const bf16x8*>(
        qp + (size_t)(qrow0 + l16) * H_ + kc * 32 + quad * 8);

  f32x4 o[16];
  #pragma unroll
  for (int ct = 0; ct < 16; ct++) o[ct] = (f32x4){0.f, 0.f, 0.f, 0.f};
  float mrow[4] = {-1e30f, -1e30f, -1e30f, -1e30f};
  float lrow[4] = {0.f, 0.f, 0.f, 0.f};

  #pragma unroll 1
  for (int kt = 0; kt < 32; kt++) {
    __syncthreads();
    #pragma unroll
    for (int i = 0; i < 4; i++) {
      int id = tid + i * 256;
      int r = id >> 5, c8 = (id & 31) * 8;
      *reinterpret_cast<uint4*>(&Ks[r][c8]) =
          *reinterpret_cast<const uint4*>(kp + (size_t)(kt * 32 + r) * H_ + c8);
    }
    #pragma unroll
    for (int i = 0; i < 4; i++) {
      int id = tid + i * 256;
      int h = id >> 2, g = id & 3;
      *reinterpret_cast<uint4*>(&Vs[h][g * 8]) =
          *reinterpret_cast<const uint4*>(vtp + (size_t)h * B_ * T_ + kt * 32 + g * 8);
    }
    __syncthreads();

    f32x4 s0 = {0.f, 0.f, 0.f, 0.f}, s1 = {0.f, 0.f, 0.f, 0.f};
    #pragma unroll
    for (int kc = 0; kc < 8; kc++) {
      bf16x8 k0 = *reinterpret_cast<const bf16x8*>(&Ks[l16][kc * 32 + quad * 8]);
      bf16x8 k1 = *reinterpret_cast<const bf16x8*>(&Ks[16 + l16][kc * 32 + quad * 8]);
      s0 = mfma16(qf[kc], k0, s0);
      s1 = mfma16(qf[kc], k1, s1);
    }
    s0 *= SCALE; s1 *= SCALE;

    float mx[4], al[4];
    #pragma unroll
    for (int r = 0; r < 4; r++) mx[r] = fmaxf(s0[r], s1[r]);
    #pragma unroll
    for (int off = 1; off < 16; off <<= 1)
      #pragma unroll
      for (int r = 0; r < 4; r++) mx[r] = fmaxf(mx[r], __shfl_xor(mx[r], off, 64));
    f32x4 p0, p1;
    float rs[4];
    #pragma unroll
    for (int r = 0; r < 4; r++) {
      float mn = fmaxf(mrow[r], mx[r]);
      al[r] = __expf(mrow[r] - mn);
      mrow[r] = mn;
      p0[r] = __expf(s0[r] - mn);
      p1[r] = __expf(s1[r] - mn);
      rs[r] = p0[r] + p1[r];
    }
    #pragma unroll
    for (int off = 1; off < 16; off <<= 1)
      #pragma unroll
      for (int r = 0; r < 4; r++) rs[r] += __shfl_xor(rs[r], off, 64);
    #pragma unroll
    for (int r = 0; r < 4; r++) lrow[r] = lrow[r] * al[r] + rs[r];

    #pragma unroll
    for (int r = 0; r < 4; r++) {
      Ps[wv][quad * 4 + r][l16]      = f2bf(p0[r]);
      Ps[wv][quad * 4 + r][16 + l16] = f2bf(p1[r]);
    }
    #pragma unroll
    for (int ct = 0; ct < 16; ct++)
      #pragma unroll
      for (int r = 0; r < 4; r++) o[ct][r] *= al[r];
    bf16x8 pf = *reinterpret_cast<const bf16x8*>(&Ps[wv][l16][quad * 8]);
    #pragma unroll
    for (int ct = 0; ct < 16; ct++) {
      bf16x8 vf = *reinterpret_cast<const bf16x8*>(&Vs[ct * 16 + l16][quad * 8]);
      o[ct] = mfma16(pf, vf, o[ct]);
    }
  }

  float invl[4];
  #pragma unroll
  for (int r = 0; r < 4; r++) invl[r] = 1.0f / lrow[r];
  u16* ob = obuf + base;
  #pragma unroll
  for (int pair = 0; pair < 8; pair++) {
    #pragma unroll
    for (int r = 0; r < 4; r++) {
      Ps[wv][quad * 4 + r][l16]      = f2bf(o[2 * pair][r] * invl[r]);
      Ps[wv][quad * 4 + r][16 + l16] = f2bf(o[2 * pair + 1][r] * invl[r]);
    }
    uint4 val = *reinterpret_cast<const uint4*>(&Ps[wv][l16][quad * 8]);
    *reinterpret_cast<uint4*>(ob + (size_t)(qrow0 + l16) * H_ + pair * 32 + quad * 8) = val;
  }
}

// ---------- K5: combine 8 branches (signed) + LayerNorm over H ----------
__global__ __launch_bounds__(256) void combine_ln2_kernel(
    const u16* __restrict__ obuf, const float* __restrict__ w,
    const float* __restrict__ bi, float* __restrict__ out) {
  const int row = blockIdx.x;
  const int h = threadIdx.x;
  float o[8];
  #pragma unroll
  for (int nn = 0; nn < 8; nn++)
    o[nn] = bf1(obuf[(size_t)nn * BT_ * H_ + (size_t)row * H_ + h]);
  float re = o[0] - o[1] - o[2] - o[3];
  float im = o[4] + o[5] + o[6] - o[7];
  float sr = re, si = im, sr2 = re * re, si2 = im * im;
  block_reduce4(sr, si, sr2, si2);
  const float inv = 1.0f / H_;
  float mr = sr * inv, mi = si * inv;
  float vr = sr2 * inv - mr * mr, vi = si2 * inv - mi * mi;
  float rr = rsqrtf(vr + EPS), ri = rsqrtf(vi + EPS);
  float ww = w[h], bb = bi[h];
  float2 res;
  res.x = (re - mr) * rr * ww + bb;
  res.y = (im - mi) * ri * ww + bb;
  reinterpret_cast<float2*>(out)[(size_t)row * H_ + h] = res;
}

extern "C" void kernel_launch(void* const* d_in, const int* in_sizes, int n_in,
                              void* d_out, int out_size, void* d_ws, size_t ws_size,
                              hipStream_t stream) {
  const float* x    = (const float*)d_in[0];
  const float* Wq   = (const float*)d_in[1];
  const float* bq   = (const float*)d_in[2];
  const float* Wk   = (const float*)d_in[3];
  const float* bk   = (const float*)d_in[4];
  const float* Wv   = (const float*)d_in[5];
  const float* bv   = (const float*)d_in[6];
  const float* ln1w = (const float*)d_in[7];
  const float* ln1b = (const float*)d_in[8];
  const float* ln2w = (const float*)d_in[9];
  const float* ln2b = (const float*)d_in[10];

  // Workspace (128 MB), lifetime-aliased:
  //  [0,8)    xnr/xni (dead after qkv)   | [0,32) vT (written by vtrans, after qkv)
  //  [8,11)   wT (dead after qkv; inside vT region, safe by ordering)
  //  [32,64)  q ; [64,96) k ; [96,128) v then obuf (v dead after vtrans)
  char* ws = (char*)d_ws;
  u16* xnr  = (u16*)(ws);
  u16* xni  = (u16*)(ws + (4ull  << 20));
  u16* wTb  = (u16*)(ws + (8ull  << 20));
  u16* vT   = (u16*)(ws);
  u16* qbuf = (u16*)(ws + (32ull << 20));
  u16* kbuf = (u16*)(ws + (64ull << 20));
  u16* vbuf = (u16*)(ws + (96ull << 20));
  u16* obuf = (u16*)(ws + (96ull << 20));

  ln1_kernel<<<BT_, 256, 0, stream>>>(x, ln1w, ln1b, xnr, xni);
  wprep_kernel<<<dim3(4, 4, 24), 256, 0, stream>>>(Wq, Wk, Wv, wTb);
  qkv_kernel<<<dim3(64, 2, 24), 256, 0, stream>>>(xnr, xni, wTb, bq, bk, bv,
                                                  qbuf, kbuf, vbuf);
  vtrans_kernel<<<dim3(16, 4, 64), 256, 0, stream>>>(vbuf, vT);
  attn_kernel<<<dim3(16, 64), 256, 0, stream>>>(qbuf, kbuf, vT, obuf);
  combine_ln2_kernel<<<BT_, 256, 0, stream>>>(obuf, ln2w, ln2b, (float*)d_out);
}

// Round 4
// 293.625 us; speedup vs baseline: 8.1276x; 1.4929x over previous
//
#include <hip/hip_runtime.h>
#include <math.h>

#define B_ 8
#define T_ 1024
#define F_ 256
#define H_ 256
#define BT_ (B_*T_)          // 8192
constexpr float EPS = 1e-5f;
constexpr float SCALE = 0.0625f;   // 1/sqrt(256), folded into qbuf (exact pow2)

typedef unsigned int u32;
typedef unsigned short u16;
typedef __attribute__((ext_vector_type(8))) short bf16x8;    // 8 bf16 = 4 VGPRs
typedef __attribute__((ext_vector_type(4))) float f32x4;
typedef __attribute__((ext_vector_type(16))) float f32x16;

// ---------- bf16 helpers ----------
__device__ __forceinline__ float bflo(u32 p) { return __uint_as_float(p << 16); }
__device__ __forceinline__ float bfhi(u32 p) { return __uint_as_float(p & 0xFFFF0000u); }
__device__ __forceinline__ float bf1(u16 p) { return __uint_as_float(((u32)p) << 16); }
__device__ __forceinline__ u16 f2bf(float f) {
  u32 u = __float_as_uint(f);
  u32 r = u + 0x7FFFu + ((u >> 16) & 1u);   // RNE
  return (u16)(r >> 16);
}

__device__ __forceinline__ f32x4 mfma16(bf16x8 a, bf16x8 b, f32x4 c) {
  return __builtin_amdgcn_mfma_f32_16x16x32_bf16(a, b, c, 0, 0, 0);
}
__device__ __forceinline__ f32x16 mfma32(bf16x8 a, bf16x8 b, f32x16 c) {
  return __builtin_amdgcn_mfma_f32_32x32x16_bf16(a, b, c, 0, 0, 0);
}

// async global->LDS, 16B per lane; dest = wave-uniform base + lane*16
__device__ __forceinline__ void gload_lds16(const u16* g, u16* l) {
  __builtin_amdgcn_global_load_lds(
      (const __attribute__((address_space(1))) u32*)(uintptr_t)g,
      (__attribute__((address_space(3))) u32*)(u32)(uintptr_t)l,
      16, 0, 0);
}

// ---------- block-wide reduction of 4 values over 256 threads ----------
__device__ __forceinline__ void block_reduce4(float& a, float& b, float& c, float& d) {
  #pragma unroll
  for (int off = 32; off > 0; off >>= 1) {
    a += __shfl_down(a, off, 64);
    b += __shfl_down(b, off, 64);
    c += __shfl_down(c, off, 64);
    d += __shfl_down(d, off, 64);
  }
  __shared__ float red[4][4];
  int wid = threadIdx.x >> 6;
  int lane = threadIdx.x & 63;
  if (lane == 0) { red[0][wid] = a; red[1][wid] = b; red[2][wid] = c; red[3][wid] = d; }
  __syncthreads();
  a = red[0][0] + red[0][1] + red[0][2] + red[0][3];
  b = red[1][0] + red[1][1] + red[1][2] + red[1][3];
  c = red[2][0] + red[2][1] + red[2][2] + red[2][3];
  d = red[3][0] + red[3][1] + red[3][2] + red[3][3];
}

// ---------- K1: LayerNorm over F per (b,t,plane); emit bf16 real/imag ----------
__global__ __launch_bounds__(256) void ln1_kernel(
    const float* __restrict__ x, const float* __restrict__ w, const float* __restrict__ bi,
    u16* __restrict__ xnr, u16* __restrict__ xni) {
  const int row = blockIdx.x;
  const int f = threadIdx.x;
  float2 xv = reinterpret_cast<const float2*>(x)[row * F_ + f];
  float sr = xv.x, si = xv.y, sr2 = xv.x * xv.x, si2 = xv.y * xv.y;
  block_reduce4(sr, si, sr2, si2);
  const float inv = 1.0f / F_;
  float mr = sr * inv, mi = si * inv;
  float vr = sr2 * inv - mr * mr, vi = si2 * inv - mi * mi;
  float rr = rsqrtf(vr + EPS), ri = rsqrtf(vi + EPS);
  float ww = w[f], bb = bi[f];
  xnr[row * F_ + f] = f2bf((xv.x - mr) * rr * ww + bb);
  xni[row * F_ + f] = f2bf((xv.y - mi) * ri * ww + bb);
}

// ---------- K2a: weight prep — transpose+convert W[z][f][h] (f32) -> wT[z][h][f] (bf16) ----------
__global__ __launch_bounds__(256) void wprep_kernel(
    const float* __restrict__ Wq, const float* __restrict__ Wk, const float* __restrict__ Wv,
    u16* __restrict__ wT) {
  const int z = blockIdx.z;
  const int m = z >> 3, n = z & 7;
  const float* W = (m == 0 ? Wq : (m == 1 ? Wk : Wv)) + (size_t)n * F_ * H_;
  const int ft = blockIdx.x * 64;
  const int ht = blockIdx.y * 64;
  __shared__ __align__(16) u16 Ts[64][72];

  const int tid = threadIdx.x;
  #pragma unroll
  for (int i = 0; i < 4; i++) {
    int id = tid + i * 256;
    int r = id >> 4, c4 = (id & 15) * 4;
    float4 p = *reinterpret_cast<const float4*>(&W[(size_t)(ft + r) * H_ + ht + c4]);
    Ts[r][c4 + 0] = f2bf(p.x); Ts[r][c4 + 1] = f2bf(p.y);
    Ts[r][c4 + 2] = f2bf(p.z); Ts[r][c4 + 3] = f2bf(p.w);
  }
  __syncthreads();
  u16* op = wT + (size_t)z * F_ * H_ + (size_t)ht * F_ + ft;
  #pragma unroll
  for (int i = 0; i < 2; i++) {
    int id = tid + i * 256;
    int hl = id & 63, g = id >> 6;
    u16 tmp[8];
    #pragma unroll
    for (int j = 0; j < 8; j++) tmp[j] = Ts[g * 8 + j][hl];
    *reinterpret_cast<uint4*>(op + (size_t)hl * F_ + g * 8) =
        *reinterpret_cast<const uint4*>(tmp);
  }
}

// ---------- K2b: QKV projections — bf16 MFMA GEMM, 128x128 tile ----------
// q outputs are pre-scaled by SCALE (exact pow2) so attention skips it.
__global__ __launch_bounds__(256) void qkv_kernel(
    const u16* __restrict__ xnr, const u16* __restrict__ xni, const u16* __restrict__ wT,
    const float* __restrict__ bq, const float* __restrict__ bk, const float* __restrict__ bv,
    u16* __restrict__ qo, u16* __restrict__ ko, u16* __restrict__ vo) {
  const int z = blockIdx.z;
  const int m = z >> 3, n = z & 7;
  int sel; const float* bias; u16* out;
  if (m == 0)      { sel = (n >> 1) & 1;  bias = bq; out = qo; }
  else if (m == 1) { sel = n & 1;         bias = bk; out = ko; }
  else             { sel = __popc(n) & 1; bias = bv; out = vo; }
  const float osc = (m == 0) ? SCALE : 1.0f;
  const u16* A = sel ? xni : xnr;
  const u16* wp = wT + (size_t)z * F_ * H_;
  bias += n * H_; out += (size_t)n * BT_ * H_;
  const int rowbase = blockIdx.x * 128;
  const int colbase = blockIdx.y * 128;

  __shared__ __align__(16) u16 As[128 * 32];
  __shared__ __align__(16) u16 Bs[128 * 32];
  __shared__ __align__(16) u16 Es[4][16][72];

  const int tid = threadIdx.x;
  const int wv = tid >> 6, lane = tid & 63;
  const int quad = lane >> 4, l16 = lane & 15;
  const int wrow = wv >> 1, wcol = wv & 1;

  f32x4 acc[4][4];
  #pragma unroll
  for (int i = 0; i < 4; i++)
    #pragma unroll
    for (int j = 0; j < 4; j++) acc[i][j] = (f32x4){0.f, 0.f, 0.f, 0.f};

  const int idx0 = (wv * 2) * 512 + lane * 8;
  const int idx1 = (wv * 2 + 1) * 512 + lane * 8;
  const int r0 = idx0 >> 5, k0 = idx0 & 31;
  const int r1 = idx1 >> 5, k1 = idx1 & 31;

  #pragma unroll 1
  for (int kb = 0; kb < F_; kb += 32) {
    gload_lds16(A + (size_t)(rowbase + r0) * F_ + kb + k0, &As[idx0]);
    gload_lds16(A + (size_t)(rowbase + r1) * F_ + kb + k1, &As[idx1]);
    gload_lds16(wp + (size_t)(colbase + r0) * F_ + kb + k0, &Bs[idx0]);
    gload_lds16(wp + (size_t)(colbase + r1) * F_ + kb + k1, &Bs[idx1]);
    __syncthreads();
    bf16x8 a[4], b[4];
    #pragma unroll
    for (int mi = 0; mi < 4; mi++)
      a[mi] = *reinterpret_cast<const bf16x8*>(
          &As[(wrow * 64 + mi * 16 + l16) * 32 + quad * 8]);
    #pragma unroll
    for (int nj = 0; nj < 4; nj++)
      b[nj] = *reinterpret_cast<const bf16x8*>(
          &Bs[(wcol * 64 + nj * 16 + l16) * 32 + quad * 8]);
    #pragma unroll
    for (int mi = 0; mi < 4; mi++)
      #pragma unroll
      for (int nj = 0; nj < 4; nj++)
        acc[mi][nj] = mfma16(a[mi], b[nj], acc[mi][nj]);
    __syncthreads();
  }

  float bias4[4];
  #pragma unroll
  for (int nj = 0; nj < 4; nj++)
    bias4[nj] = bias[colbase + wcol * 64 + nj * 16 + l16];
  #pragma unroll
  for (int mi = 0; mi < 4; mi++) {
    #pragma unroll
    for (int nj = 0; nj < 4; nj++)
      #pragma unroll
      for (int r = 0; r < 4; r++)
        Es[wv][quad * 4 + r][nj * 16 + l16] = f2bf((acc[mi][nj][r] + bias4[nj]) * osc);
    int row = rowbase + wrow * 64 + mi * 16 + l16;
    uint4 v0 = *reinterpret_cast<const uint4*>(&Es[wv][l16][quad * 16]);
    uint4 v1 = *reinterpret_cast<const uint4*>(&Es[wv][l16][quad * 16 + 8]);
    u16* op = out + (size_t)row * H_ + colbase + wcol * 64 + quad * 16;
    *reinterpret_cast<uint4*>(op) = v0;
    *reinterpret_cast<uint4*>(op + 8) = v1;
  }
}

// ---------- K3: transpose v [n][BT][H] -> vT [n][H][B][T] ----------
__global__ __launch_bounds__(256) void vtrans_kernel(
    const u16* __restrict__ v, u16* __restrict__ vT) {
  const int nb = blockIdx.z;
  const int n = nb >> 3, b = nb & 7;
  const int tt = blockIdx.x;
  const int ht = blockIdx.y;
  __shared__ u16 Ts[64][72];

  const int tid = threadIdx.x;
  const u16* vp = v + ((size_t)n * BT_ + b * T_ + tt * 64) * H_ + ht * 64;
  #pragma unroll
  for (int i = 0; i < 2; i++) {
    int id = tid + i * 256;
    int r = id >> 3, c8 = (id & 7) * 8;
    *reinterpret_cast<uint4*>(&Ts[r][c8]) =
        *reinterpret_cast<const uint4*>(vp + (size_t)r * H_ + c8);
  }
  __syncthreads();
  u16* op = vT + (((size_t)n * H_ + ht * 64) * B_ + b) * T_ + tt * 64;
  #pragma unroll
  for (int i = 0; i < 2; i++) {
    int id = tid + i * 256;
    int hl = id & 63, g = id >> 6;
    u16 tmp[8];
    #pragma unroll
    for (int j = 0; j < 8; j++) tmp[j] = Ts[g * 8 + j][hl];
    *reinterpret_cast<uint4*>(op + (size_t)hl * B_ * T_ + g * 8) =
        *reinterpret_cast<const uint4*>(tmp);
  }
}

// ---------- K4: MFMA flash attention, 32x32x16, max-free softmax ----------
// Block: 64 q-rows, K-tile 64 keys, 16 iters. Waves: QK role (qh=wv>>1, kh=wv&1),
// PV role (qh=wv>>1, hh=wv&1). V staged in two 128-h halves (LDS budget).
// obuf layout: [n][ht=8][8192][32] (blocked h), consumed by combine_ln2.
__global__ __launch_bounds__(256, 2) void attn_kernel(
    const u16* __restrict__ q, const u16* __restrict__ k, const u16* __restrict__ vT,
    u16* __restrict__ obuf) {
  const int qt = blockIdx.x;         // 0..15 : 64 query rows
  const int nb = blockIdx.y;         // n*8 + b
  const int n = nb >> 3, b = nb & 7;
  const int tid = threadIdx.x;
  const int wv = tid >> 6, lane = tid & 63;
  const int hi = lane >> 5, l32 = lane & 31;
  const int qh = wv >> 1;            // q-half (32 rows)
  const int kh = wv & 1;             // QK: key-half (32 keys)
  const int hh = wv & 1;             // PV: h-half-of-half (64 h per phase)

  const size_t base = (size_t)nb * T_ * H_;
  const u16* qp = q + base;          // pre-scaled by SCALE
  const u16* kp = k + base;
  const u16* vtp = vT + ((size_t)n * H_ * B_ + b) * T_;

  __shared__ __align__(16) u16 Ks[64][264];    // [key][feat], 528B rows
  __shared__ __align__(16) u16 Vs[128][72];    // [h within half][key], 144B rows
  __shared__ __align__(16) u16 Ps[2][32][72];  // [qh][qrow][key 0..63]
  __shared__ float Ls[2][2][32];               // [qh][kh][qrow] partial l

  // Q fragments: rows qt*64+qh*32 + l32, A-layout m=l32, k=hi*8+j (+16*kc)
  const int qrow0 = qt * 64 + qh * 32;
  bf16x8 qf[16];
  #pragma unroll
  for (int kc = 0; kc < 16; kc++)
    qf[kc] = *reinterpret_cast<const bf16x8*>(
        qp + (size_t)(qrow0 + l32) * H_ + kc * 16 + hi * 8);

  f32x16 o[4];                       // 4 h-tiles of 32 (total 128 h per wave)
  #pragma unroll
  for (int ot = 0; ot < 4; ot++)
    #pragma unroll
    for (int r = 0; r < 16; r++) o[ot][r] = 0.f;
  float lper[16];
  #pragma unroll
  for (int r = 0; r < 16; r++) lper[r] = 0.f;

  const int krow = tid >> 2, kch = tid & 3;    // K staging map
  const int vrow = tid >> 1, vch = tid & 1;    // V staging map

  #pragma unroll 1
  for (int kt = 0; kt < 16; kt++) {
    __syncthreads();   // b_top: prev PV1 reads done
    {  // stage K tile 64x256
      uint4 kreg[8];
      #pragma unroll
      for (int i = 0; i < 8; i++)
        kreg[i] = *reinterpret_cast<const uint4*>(
            kp + (size_t)(kt * 64 + krow) * H_ + kch * 8 + i * 32);
      #pragma unroll
      for (int i = 0; i < 8; i++)
        *reinterpret_cast<uint4*>(&Ks[krow][kch * 8 + i * 32]) = kreg[i];
    }
    {  // stage V half 0: h 0..127
      uint4 vreg[4];
      #pragma unroll
      for (int i = 0; i < 4; i++)
        vreg[i] = *reinterpret_cast<const uint4*>(
            vtp + (size_t)vrow * (B_ * T_) + kt * 64 + vch * 32 + i * 8);
      #pragma unroll
      for (int i = 0; i < 4; i++)
        *reinterpret_cast<uint4*>(&Vs[vrow][vch * 32 + i * 8]) = vreg[i];
    }
    __syncthreads();   // b1: staging visible

    // S = Q K^T for (qh 32 rows) x (kh 32 keys), two interleaved chains
    f32x16 sa, sb;
    #pragma unroll
    for (int r = 0; r < 16; r++) { sa[r] = 0.f; sb[r] = 0.f; }
    #pragma unroll
    for (int kc = 0; kc < 16; kc += 2) {
      bf16x8 kfa = *reinterpret_cast<const bf16x8*>(
          &Ks[kh * 32 + l32][kc * 16 + hi * 8]);
      bf16x8 kfb = *reinterpret_cast<const bf16x8*>(
          &Ks[kh * 32 + l32][(kc + 1) * 16 + hi * 8]);
      sa = mfma32(qf[kc], kfa, sa);
      sb = mfma32(qf[kc + 1], kfb, sb);
    }
    // P = exp(S), accumulate l, write P to LDS (C/D -> A transform)
    #pragma unroll
    for (int r = 0; r < 16; r++) {
      float p = __expf(sa[r] + sb[r]);
      lper[r] += p;
      int row = (r & 3) + 8 * (r >> 2) + 4 * hi;
      Ps[qh][row][kh * 32 + l32] = f2bf(p);
    }
    __syncthreads();   // b2: P visible

    bf16x8 pa[4];
    #pragma unroll
    for (int kc2 = 0; kc2 < 4; kc2++)
      pa[kc2] = *reinterpret_cast<const bf16x8*>(
          &Ps[qh][l32][kc2 * 16 + hi * 8]);
    #pragma unroll
    for (int j = 0; j < 2; j++)      // PV phase 0: h 0..127
      #pragma unroll
      for (int kc2 = 0; kc2 < 4; kc2++) {
        bf16x8 vf = *reinterpret_cast<const bf16x8*>(
            &Vs[hh * 64 + j * 32 + l32][kc2 * 16 + hi * 8]);
        o[j] = mfma32(pa[kc2], vf, o[j]);
      }
    __syncthreads();   // b3: PV0 reads done
    {  // stage V half 1: h 128..255
      uint4 vreg[4];
      #pragma unroll
      for (int i = 0; i < 4; i++)
        vreg[i] = *reinterpret_cast<const uint4*>(
            vtp + (size_t)(128 + vrow) * (B_ * T_) + kt * 64 + vch * 32 + i * 8);
      #pragma unroll
      for (int i = 0; i < 4; i++)
        *reinterpret_cast<uint4*>(&Vs[vrow][vch * 32 + i * 8]) = vreg[i];
    }
    __syncthreads();   // b4: V1 visible
    #pragma unroll
    for (int j = 0; j < 2; j++)      // PV phase 1: h 128..255
      #pragma unroll
      for (int kc2 = 0; kc2 < 4; kc2++) {
        bf16x8 vf = *reinterpret_cast<const bf16x8*>(
            &Vs[hh * 64 + j * 32 + l32][kc2 * 16 + hi * 8]);
        o[2 + j] = mfma32(pa[kc2], vf, o[2 + j]);
      }
  }

  // l: reduce across the 32 key-columns (lanes of same hi), publish per kh
  #pragma unroll
  for (int r = 0; r < 16; r++) {
    #pragma unroll
    for (int off = 1; off < 32; off <<= 1)
      lper[r] += __shfl_xor(lper[r], off, 64);
  }
  if (l32 == 0) {
    #pragma unroll
    for (int r = 0; r < 16; r++)
      Ls[qh][kh][(r & 3) + 8 * (r >> 2) + 4 * hi] = lper[r];
  }
  __syncthreads();

  float invl[16];
  #pragma unroll
  for (int r = 0; r < 16; r++) {
    int row = (r & 3) + 8 * (r >> 2) + 4 * hi;
    invl[r] = 1.0f / (Ls[qh][0][row] + Ls[qh][1][row]);
  }

  // epilogue: per o-tile normalize, repack via LDS (aliased into Ks), store
  u16* Ew = reinterpret_cast<u16*>(&Ks[0][0]) + wv * 1280;   // [32][40] per wave
  const int grow = b * 1024 + qrow0 + l32;
  #pragma unroll
  for (int ot = 0; ot < 4; ot++) {
    #pragma unroll
    for (int r = 0; r < 16; r++) {
      int row = (r & 3) + 8 * (r >> 2) + 4 * hi;
      Ew[row * 40 + l32] = f2bf(o[ot][r] * invl[r]);
    }
    int ht = (ot >> 1) * 4 + hh * 2 + (ot & 1);
    uint4 v0 = *reinterpret_cast<const uint4*>(&Ew[l32 * 40 + hi * 16]);
    uint4 v1 = *reinterpret_cast<const uint4*>(&Ew[l32 * 40 + hi * 16 + 8]);
    u16* op = obuf + (((size_t)n * 8 + ht) * BT_ + grow) * 32 + hi * 16;
    *reinterpret_cast<uint4*>(op) = v0;
    *reinterpret_cast<uint4*>(op + 8) = v1;
  }
}

// ---------- K5: combine 8 branches (signed) + LayerNorm over H ----------
// obuf blocked layout: [n][ht=8][8192][32]
__global__ __launch_bounds__(256) void combine_ln2_kernel(
    const u16* __restrict__ obuf, const float* __restrict__ w,
    const float* __restrict__ bi, float* __restrict__ out) {
  const int row = blockIdx.x;
  const int h = threadIdx.x;
  float o[8];
  #pragma unroll
  for (int nn = 0; nn < 8; nn++)
    o[nn] = bf1(obuf[(((size_t)nn * 8 + (h >> 5)) * BT_ + row) * 32 + (h & 31)]);
  float re = o[0] - o[1] - o[2] - o[3];
  float im = o[4] + o[5] + o[6] - o[7];
  float sr = re, si = im, sr2 = re * re, si2 = im * im;
  block_reduce4(sr, si, sr2, si2);
  const float inv = 1.0f / H_;
  float mr = sr * inv, mi = si * inv;
  float vr = sr2 * inv - mr * mr, vi = si2 * inv - mi * mi;
  float rr = rsqrtf(vr + EPS), ri = rsqrtf(vi + EPS);
  float ww = w[h], bb = bi[h];
  float2 res;
  res.x = (re - mr) * rr * ww + bb;
  res.y = (im - mi) * ri * ww + bb;
  reinterpret_cast<float2*>(out)[(size_t)row * H_ + h] = res;
}

extern "C" void kernel_launch(void* const* d_in, const int* in_sizes, int n_in,
                              void* d_out, int out_size, void* d_ws, size_t ws_size,
                              hipStream_t stream) {
  const float* x    = (const float*)d_in[0];
  const float* Wq   = (const float*)d_in[1];
  const float* bq   = (const float*)d_in[2];
  const float* Wk   = (const float*)d_in[3];
  const float* bk   = (const float*)d_in[4];
  const float* Wv   = (const float*)d_in[5];
  const float* bv   = (const float*)d_in[6];
  const float* ln1w = (const float*)d_in[7];
  const float* ln1b = (const float*)d_in[8];
  const float* ln2w = (const float*)d_in[9];
  const float* ln2b = (const float*)d_in[10];

  // Workspace (128 MB), lifetime-aliased:
  //  [0,8) xnr/xni (dead after qkv) | [0,32) vT | [8,11) wT (dead after qkv)
  //  [32,64) q ; [64,96) k ; [96,128) v then obuf (v dead after vtrans)
  char* ws = (char*)d_ws;
  u16* xnr  = (u16*)(ws);
  u16* xni  = (u16*)(ws + (4ull  << 20));
  u16* wTb  = (u16*)(ws + (8ull  << 20));
  u16* vT   = (u16*)(ws);
  u16* qbuf = (u16*)(ws + (32ull << 20));
  u16* kbuf = (u16*)(ws + (64ull << 20));
  u16* vbuf = (u16*)(ws + (96ull << 20));
  u16* obuf = (u16*)(ws + (96ull << 20));

  ln1_kernel<<<BT_, 256, 0, stream>>>(x, ln1w, ln1b, xnr, xni);
  wprep_kernel<<<dim3(4, 4, 24), 256, 0, stream>>>(Wq, Wk, Wv, wTb);
  qkv_kernel<<<dim3(64, 2, 24), 256, 0, stream>>>(xnr, xni, wTb, bq, bk, bv,
                                                  qbuf, kbuf, vbuf);
  vtrans_kernel<<<dim3(16, 4, 64), 256, 0, stream>>>(vbuf, vT);
  attn_kernel<<<dim3(16, 64), 256, 0, stream>>>(qbuf, kbuf, vT, obuf);
  combine_ln2_kernel<<<BT_, 256, 0, stream>>>(obuf, ln2w, ln2b, (float*)d_out);
}